// Round 2
// baseline (1839.695 us; speedup 1.0000x reference)
//
#include <hip/hip_runtime.h>

#define Bc 4
#define Cc 64
#define Nc 8192
#define Kc 40
#define CN (Cc * Nc)   // 524288

// ---------------------------------------------------------------- aa kernel
__global__ __launch_bounds__(256) void aa_kernel(const float* __restrict__ x,
                                                 float* __restrict__ aa) {
  const int e = blockIdx.x * 256 + threadIdx.x;  // 0..32767
  const int b = e >> 13, n = e & 8191;
  const float* xb = x + (size_t)b * CN + n;
  float s = 0.f;
#pragma unroll
  for (int c = 0; c < 64; ++c) {
    const float v = xb[c * Nc];
    s = fmaf(v, v, s);
  }
  aa[e] = s;
}

// ---------------------------------------------------------------- projection
// qp/kp/vp[b][n][o] = sum_c W[o][c] * x[b][c][n]
__global__ __launch_bounds__(256) void proj_kernel(
    const float* __restrict__ x, const float* __restrict__ Wq,
    const float* __restrict__ Wk, const float* __restrict__ Wv,
    float* __restrict__ qp, float* __restrict__ kp, float* __restrict__ vp) {
  __shared__ float xs[64 * 64];  // [c][p]
  __shared__ float wt[64 * 64];  // [c][o]
  const int t = threadIdx.x;
  const int w = t >> 6, lane = t & 63;
  const int b = blockIdx.x >> 7;
  const int n0 = (blockIdx.x & 127) << 6;
  const float* xb = x + (size_t)b * CN;
  for (int c = w; c < 64; c += 4) xs[c * 64 + lane] = xb[c * Nc + n0 + lane];

  const float* Ws[3] = {Wq, Wk, Wv};
  float* Ds[3] = {qp, kp, vp};
  for (int mtx = 0; mtx < 3; ++mtx) {
    __syncthreads();
    const float* W = Ws[mtx];
    for (int q = t; q < 4096; q += 256) {
      const int o = q & 63, c = q >> 6;
      wt[c * 64 + o] = W[o * 64 + c];
    }
    __syncthreads();
    float acc[16];
#pragma unroll
    for (int k = 0; k < 16; ++k) acc[k] = 0.f;
#pragma unroll 8
    for (int c = 0; c < 64; ++c) {
      const float xv = xs[c * 64 + lane];
      const float4 w0 = *(const float4*)&wt[c * 64 + w * 16 + 0];
      const float4 w1 = *(const float4*)&wt[c * 64 + w * 16 + 4];
      const float4 w2 = *(const float4*)&wt[c * 64 + w * 16 + 8];
      const float4 w3 = *(const float4*)&wt[c * 64 + w * 16 + 12];
      acc[0] = fmaf(xv, w0.x, acc[0]);   acc[1] = fmaf(xv, w0.y, acc[1]);
      acc[2] = fmaf(xv, w0.z, acc[2]);   acc[3] = fmaf(xv, w0.w, acc[3]);
      acc[4] = fmaf(xv, w1.x, acc[4]);   acc[5] = fmaf(xv, w1.y, acc[5]);
      acc[6] = fmaf(xv, w1.z, acc[6]);   acc[7] = fmaf(xv, w1.w, acc[7]);
      acc[8] = fmaf(xv, w2.x, acc[8]);   acc[9] = fmaf(xv, w2.y, acc[9]);
      acc[10] = fmaf(xv, w2.z, acc[10]); acc[11] = fmaf(xv, w2.w, acc[11]);
      acc[12] = fmaf(xv, w3.x, acc[12]); acc[13] = fmaf(xv, w3.y, acc[13]);
      acc[14] = fmaf(xv, w3.z, acc[14]); acc[15] = fmaf(xv, w3.w, acc[15]);
    }
    float* dst = Ds[mtx] + ((size_t)(b * Nc + n0 + lane)) * 64 + w * 16;
    *(float4*)(dst + 0) = make_float4(acc[0], acc[1], acc[2], acc[3]);
    *(float4*)(dst + 4) = make_float4(acc[4], acc[5], acc[6], acc[7]);
    *(float4*)(dst + 8) = make_float4(acc[8], acc[9], acc[10], acc[11]);
    *(float4*)(dst + 12) = make_float4(acc[12], acc[13], acc[14], acc[15]);
  }
}

// ---------------------------------------------------------------- KNN top-40
// pd = 2*inner - aa_i - aa_j ; keep the 40-largest SET per row.
// 128x128 tile per block, 8x8 per thread (cols split {tx*4, 64+tx*4} for
// conflict-free b128), per-row queue cap 64 (hard bound: 64 cols/sub-phase),
// two owner threads per row (entry-parity partition), final 40+40 merge.
__global__ __launch_bounds__(256, 1) void knn_kernel(const float* __restrict__ x,
                                                     const float* __restrict__ aa,
                                                     int* __restrict__ knn) {
  __shared__ float rowT[64][128];          // [c][r] 32KB
  __shared__ float colT[64][128];          // [c][j] 32KB
  __shared__ float qv[128][64];            // 32KB
  __shared__ unsigned short qidx[128][64]; // 16KB
  __shared__ float thrS[128][2];
  __shared__ int qcnt[128];

  const int t = threadIdx.x;
  const int ty = t >> 4;   // 0..15 -> rows ty*8..+7
  const int tx = t & 15;   // 0..15 -> cols {tx*4..+3} and {64+tx*4..+3}
  const int b = blockIdx.x >> 6;
  const int i0 = (blockIdx.x & 63) << 7;
  const float* xb = x + (size_t)b * CN;
  const float* aab = aa + b * Nc;

  if (t < 128) { qcnt[t] = 0; thrS[t][0] = -INFINITY; thrS[t][1] = -INFINITY; }

  const int cSub = t >> 4;   // reuse as staging c-lane
  const int chunk = t & 15;  // staging 8-float chunk
  for (int cc = 0; cc < 4; ++cc) {
    const int c = cc * 16 + cSub;
    const float* src = xb + (size_t)c * Nc + i0 + chunk * 8;
    const float4 v0 = ((const float4*)src)[0];
    const float4 v1 = ((const float4*)src)[1];
    *(float4*)&rowT[c][chunk * 8] = v0;
    *(float4*)&rowT[c][chunk * 8 + 4] = v1;
  }

  float rA[8];
  {
    const float4 r0 = *(const float4*)&aab[i0 + ty * 8];
    const float4 r1 = *(const float4*)&aab[i0 + ty * 8 + 4];
    rA[0] = r0.x; rA[1] = r0.y; rA[2] = r0.z; rA[3] = r0.w;
    rA[4] = r1.x; rA[5] = r1.y; rA[6] = r1.z; rA[7] = r1.w;
  }

  float lv[40]; int li[40];
#pragma unroll
  for (int q = 0; q < 40; ++q) { lv[q] = -INFINITY; li[q] = 0; }
  float lmin = -INFINITY; int lminpos = 0;

  const int dr = t >> 1, slot = t & 1;

  auto insert = [&](float v, int idx) {
#pragma unroll
    for (int q = 0; q < 40; ++q)
      if (q == lminpos) { lv[q] = v; li[q] = idx; }
    float nm = lv[0]; int np = 0;
#pragma unroll
    for (int q = 1; q < 40; ++q) {
      if (lv[q] < nm) { nm = lv[q]; np = q; }
    }
    lmin = nm; lminpos = np;
  };

  for (int jt = 0; jt < 64; ++jt) {
    const int j0 = jt << 7;
    // stage colT (prior phase fully synced at loop bottom / init path)
    for (int cc = 0; cc < 4; ++cc) {
      const int c = cc * 16 + cSub;
      const float* src = xb + (size_t)c * Nc + j0 + chunk * 8;
      const float4 v0 = ((const float4*)src)[0];
      const float4 v1 = ((const float4*)src)[1];
      *(float4*)&colT[c][chunk * 8] = v0;
      *(float4*)&colT[c][chunk * 8 + 4] = v1;
    }
    __syncthreads();

    float acc[8][8];
#pragma unroll
    for (int i = 0; i < 8; ++i)
#pragma unroll
      for (int jj = 0; jj < 8; ++jj) acc[i][jj] = 0.f;

#pragma unroll 2
    for (int c = 0; c < 64; ++c) {
      const float4 a0 = *(const float4*)&rowT[c][ty * 8];
      const float4 a1 = *(const float4*)&rowT[c][ty * 8 + 4];
      const float4 b0 = *(const float4*)&colT[c][tx * 4];
      const float4 b1 = *(const float4*)&colT[c][64 + tx * 4];
      const float av[8] = {a0.x, a0.y, a0.z, a0.w, a1.x, a1.y, a1.z, a1.w};
      const float bv[8] = {b0.x, b0.y, b0.z, b0.w, b1.x, b1.y, b1.z, b1.w};
#pragma unroll
      for (int i = 0; i < 8; ++i)
#pragma unroll
        for (int jj = 0; jj < 8; ++jj)
          acc[i][jj] = fmaf(av[i], bv[jj], acc[i][jj]);
    }

    float cA[8];
    {
      const float4 c0 = *(const float4*)&aab[j0 + tx * 4];
      const float4 c1 = *(const float4*)&aab[j0 + 64 + tx * 4];
      cA[0] = c0.x; cA[1] = c0.y; cA[2] = c0.z; cA[3] = c0.w;
      cA[4] = c1.x; cA[5] = c1.y; cA[6] = c1.z; cA[7] = c1.w;
    }

    for (int half = 0; half < 2; ++half) {
      float th8[8];
      {
        const float4* tp = (const float4*)&thrS[ty * 8][0];
        const float4 u0 = tp[0], u1 = tp[1], u2 = tp[2], u3 = tp[3];
        th8[0] = fminf(u0.x, u0.y); th8[1] = fminf(u0.z, u0.w);
        th8[2] = fminf(u1.x, u1.y); th8[3] = fminf(u1.z, u1.w);
        th8[4] = fminf(u2.x, u2.y); th8[5] = fminf(u2.z, u2.w);
        th8[6] = fminf(u3.x, u3.y); th8[7] = fminf(u3.z, u3.w);
      }
#pragma unroll
      for (int i = 0; i < 8; ++i) {
        const int r = ty * 8 + i;
#pragma unroll
        for (int jq = 0; jq < 4; ++jq) {
          const int jj = half * 4 + jq;
          const float v = 2.0f * acc[i][jj] - rA[i] - cA[jj];
          if (v > th8[i]) {
            const int pos = atomicAdd(&qcnt[r], 1);
            qv[r][pos] = v;
            qidx[r][pos] = (unsigned short)(j0 + half * 64 + tx * 4 + jq);
          }
        }
      }
      __syncthreads();
      {
        int cnt = qcnt[dr]; if (cnt > 64) cnt = 64;
        for (int e = slot; e < cnt; e += 2) {
          const float v = qv[dr][e];
          if (v > lmin) insert(v, (int)qidx[dr][e]);
        }
        if (slot == 0) qcnt[dr] = 0;
        thrS[dr][slot] = lmin;
      }
      __syncthreads();
    }
  }

  // merge the two per-row partial top-40s (union contains the true top-40)
  if (slot == 1) {
#pragma unroll
    for (int q = 0; q < 40; ++q) {
      qv[dr][q] = lv[q];
      qidx[dr][q] = (unsigned short)li[q];
    }
  }
  __syncthreads();
  if (slot == 0) {
#pragma unroll
    for (int q = 0; q < 40; ++q) {
      const float v = qv[dr][q];
      if (v > lmin) insert(v, (int)qidx[dr][q]);
    }
    int* dst = knn + (size_t)(b * Nc + i0 + dr) * Kc;
#pragma unroll
    for (int q = 0; q < 40; ++q) dst[q] = li[q];
  }
}

// ---------------------------------------------------------------- attention
// one wave per point; lane = channel; out = sum_j a_j*vp[j] - vp[n]; y = x + out
__global__ __launch_bounds__(256) void attn_kernel(
    const float* __restrict__ x, const float* __restrict__ qp,
    const float* __restrict__ kp, const float* __restrict__ vp,
    const int* __restrict__ knn, float* __restrict__ y) {
  const int lane = threadIdx.x & 63;
  const int wid = threadIdx.x >> 6;
  const int pt = (blockIdx.x << 2) + wid;  // 0..32767
  const int b = pt >> 13;
  const int nn = pt & 8191;
  const float q = qp[(size_t)pt * 64 + lane];
  const float vself = vp[(size_t)pt * 64 + lane];
  const float* kpb = kp + (size_t)b * (Nc * 64);
  const float* vpb = vp + (size_t)b * (Nc * 64);
  const int* idn = knn + (size_t)pt * Kc;
  float e[40], vv[40];
#pragma unroll
  for (int j = 0; j < 40; ++j) {
    const int ij = idn[j];
    const float kj = kpb[ij * 64 + lane];
    vv[j] = vpb[ij * 64 + lane];
    float p = q * kj;
    p += __shfl_xor(p, 1);
    p += __shfl_xor(p, 2);
    p += __shfl_xor(p, 4);
    p += __shfl_xor(p, 8);
    e[j] = p * 0.25f;  // /sqrt(16)
  }
  float m = e[0];
#pragma unroll
  for (int j = 1; j < 40; ++j) m = fmaxf(m, e[j]);
  float s = 0.f;
#pragma unroll
  for (int j = 0; j < 40; ++j) { e[j] = __expf(e[j] - m); s += e[j]; }
  const float inv = 1.f / s;
  float acc = 0.f;
#pragma unroll
  for (int j = 0; j < 40; ++j) acc = fmaf(e[j] * inv, vv[j], acc);
  const size_t xi = (size_t)b * CN + (size_t)lane * Nc + nn;
  y[xi] = x[xi] + (acc - vself);
}

// ---------------------------------------------------------------- BN stats
__global__ __launch_bounds__(256) void stats_kernel(const float* __restrict__ src,
                                                    float* __restrict__ out) {
  const int c = blockIdx.x;
  float s = 0.f, s2 = 0.f;
  for (int b = 0; b < Bc; ++b) {
    const float* p = src + (size_t)b * CN + (size_t)c * Nc;
    for (int i = threadIdx.x; i < Nc; i += 256) {
      const float v = p[i];
      s += v;
      s2 = fmaf(v, v, s2);
    }
  }
  __shared__ float rs[256], rs2[256];
  rs[threadIdx.x] = s; rs2[threadIdx.x] = s2;
  __syncthreads();
  for (int st = 128; st > 0; st >>= 1) {
    if (threadIdx.x < st) {
      rs[threadIdx.x] += rs[threadIdx.x + st];
      rs2[threadIdx.x] += rs2[threadIdx.x + st];
    }
    __syncthreads();
  }
  if (threadIdx.x == 0) {
    const float mean = rs[0] * (1.f / 32768.f);
    const float var = rs2[0] * (1.f / 32768.f) - mean * mean;
    out[c] = mean;
    out[64 + c] = 1.f / sqrtf(var + 1e-5f);
  }
}

// ---------------------------------------------------------------- W2 transpose
__global__ __launch_bounds__(256) void w2t_kernel(const float* __restrict__ W2,
                                                  float* __restrict__ W2t) {
  const int e = blockIdx.x * 256 + threadIdx.x;  // 16384
  const int o = e >> 6, c = e & 63;
  W2t[e] = W2[c * 256 + o];  // W2t[o][c]
}

// ---------------------------------------------------------------- FFN fused
__global__ __launch_bounds__(256) void ffn_kernel(
    const float* __restrict__ y, const float* __restrict__ W1,
    const float* __restrict__ W2t, const float* __restrict__ st1,
    const float* __restrict__ g1, const float* __restrict__ b1,
    float* __restrict__ z) {
  const int pt = blockIdx.x * 256 + threadIdx.x;  // 0..32767
  const int b = pt >> 13, nn = pt & 8191;
  const float* yb = y + (size_t)b * CN + nn;
  float x1[64], z0[64];
#pragma unroll
  for (int c = 0; c < 64; ++c) {
    const float sc = st1[64 + c] * g1[c];
    x1[c] = (yb[(size_t)c * Nc] - st1[c]) * sc + b1[c];
    z0[c] = x1[c];
  }
  for (int o = 0; o < 256; ++o) {
    const float* w1r = W1 + o * 64;
    float hv = 0.f;
#pragma unroll
    for (int c = 0; c < 64; ++c) hv = fmaf(w1r[c], x1[c], hv);
    hv = hv >= 0.f ? hv : 0.2f * hv;
    const float* w2r = W2t + o * 64;
#pragma unroll
    for (int c = 0; c < 64; ++c) z0[c] = fmaf(w2r[c], hv, z0[c]);
  }
  float* zb = z + (size_t)b * CN + nn;
#pragma unroll
  for (int c = 0; c < 64; ++c) zb[(size_t)c * Nc] = z0[c];
}

// ---------------------------------------------------------------- BN apply
__global__ __launch_bounds__(256) void bn_apply_kernel(
    const float* __restrict__ z, const float* __restrict__ st2,
    const float* __restrict__ g2, const float* __restrict__ b2,
    float* __restrict__ out) {
  const int e = blockIdx.x * 256 + threadIdx.x;  // 2097152
  const int c = (e >> 13) & 63;
  const float sc = st2[64 + c] * g2[c];
  out[e] = (z[e] - st2[c]) * sc + b2[c];
}

// ---------------------------------------------------------------- launch
extern "C" void kernel_launch(void* const* d_in, const int* in_sizes, int n_in,
                              void* d_out, int out_size, void* d_ws, size_t ws_size,
                              hipStream_t stream) {
  (void)in_sizes; (void)n_in; (void)out_size; (void)ws_size;
  const float* x  = (const float*)d_in[0];
  const float* Wq = (const float*)d_in[1];
  const float* Wk = (const float*)d_in[2];
  const float* Wv = (const float*)d_in[3];
  const float* W1 = (const float*)d_in[4];
  const float* W2 = (const float*)d_in[5];
  const float* g1 = (const float*)d_in[6];
  const float* b1 = (const float*)d_in[7];
  const float* g2 = (const float*)d_in[8];
  const float* b2 = (const float*)d_in[9];
  float* out = (float*)d_out;

  float* ws = (float*)d_ws;
  float* aa  = ws;                 // 32768
  float* qp  = aa + 32768;         // 2097152
  float* kp  = qp + 2097152;       // 2097152
  float* vp  = kp + 2097152;       // 2097152
  float* y   = vp + 2097152;       // 2097152
  float* z   = y + 2097152;        // 2097152
  float* st1 = z + 2097152;        // 128
  float* st2 = st1 + 128;          // 128
  float* W2t = st2 + 128;          // 16384
  int* knn   = (int*)(W2t + 16384);// 1310720 ints

  hipLaunchKernelGGL(aa_kernel, dim3(128), dim3(256), 0, stream, x, aa);
  hipLaunchKernelGGL(proj_kernel, dim3(512), dim3(256), 0, stream, x, Wq, Wk, Wv, qp, kp, vp);
  hipLaunchKernelGGL(knn_kernel, dim3(256), dim3(256), 0, stream, x, aa, knn);
  hipLaunchKernelGGL(attn_kernel, dim3(8192), dim3(256), 0, stream, x, qp, kp, vp, knn, y);
  hipLaunchKernelGGL(stats_kernel, dim3(64), dim3(256), 0, stream, y, st1);
  hipLaunchKernelGGL(w2t_kernel, dim3(64), dim3(256), 0, stream, W2, W2t);
  hipLaunchKernelGGL(ffn_kernel, dim3(128), dim3(256), 0, stream, y, W1, W2t, st1, g1, b1, z);
  hipLaunchKernelGGL(stats_kernel, dim3(64), dim3(256), 0, stream, z, st2);
  hipLaunchKernelGGL(bn_apply_kernel, dim3(8192), dim3(256), 0, stream, z, st2, g2, b2, out);
}